// Round 2
// baseline (77.764 us; speedup 1.0000x reference)
//
#include <hip/hip_runtime.h>
#include <hip/hip_fp16.h>

static constexpr int W56 = 56;
static constexpr int SP  = 56 * 56;   // 3136 = 49*64
static constexpr int CHN = 64;

// ---------------------------------------------------------------------------
// Prep kernel (one-shot, tiny): fp32 LUT (16cb x 16e x 64ch = 64KB) -> fp16
// (32KB) in d_ws, pre-swizzled per 16B chunk.
// Linear slot r*8+c stores logical chunk (c ^ (r&7)) of row r, so the main
// kernel stages ws -> LDS with linear global_load_lds while phase-2 reads
// chunk (2q+i)^(row&7): per-row XOR rotation -> only e vs e+8 alias (free
// 2-way bank conflict).
// ---------------------------------------------------------------------------
__global__ __launch_bounds__(256) void lut_prep(const float* __restrict__ lut,
                                                __half* __restrict__ wlut) {
    const int t = blockIdx.x * 256 + threadIdx.x;   // 0..2047 (one 16B chunk each)
    const int r = t >> 3;
    const int c = (t & 7) ^ (r & 7);                // logical chunk for this slot
    const float4* src = reinterpret_cast<const float4*>(lut + r * 64 + c * 8);
    const float4 f0 = src[0];
    const float4 f1 = src[1];
    __half2 h[4];
    h[0] = __float22half2_rn(make_float2(f0.x, f0.y));
    h[1] = __float22half2_rn(make_float2(f0.z, f0.w));
    h[2] = __float22half2_rn(make_float2(f1.x, f1.y));
    h[3] = __float22half2_rn(make_float2(f1.z, f1.w));
    *reinterpret_cast<float4*>(wlut + t * 8) = *reinterpret_cast<const float4*>(h);
}

// async global -> LDS, 16B per lane (dest = uniform base + lane*16)
__device__ __forceinline__ void async_copy16(const void* g, void* l) {
    __builtin_amdgcn_global_load_lds(
        (const __attribute__((address_space(1))) void*)g,
        (__attribute__((address_space(3))) void*)l,
        16, 0, 0);
}

// ---------------------------------------------------------------------------
// Fused kernel, 2 point-groups per block. grid = 392 (= 50176/128), block 256.
// Every block is co-resident (<=2 blocks/CU) -> no sequential residency
// rounds; 32 gather loads per thread in flight before first use; LUT staged
// once per 128 points (was once per 64).
// Schedule: gathers g0 -> async LUT stage -> gathers g1 -> encode g0 ->
//           barrier -> encode g1 | decode g0 -> barrier -> decode g1.
// ---------------------------------------------------------------------------
__global__ __launch_bounds__(256, 2) void maddness_fused(
    const float*  __restrict__ x,
    const int*    __restrict__ si,
    const float*  __restrict__ sv,
    const __half* __restrict__ wlut,
    const float*  __restrict__ bias,
    float*        __restrict__ out)
{
    __shared__ __half2        lutLds[256 * 32];   // packed, chunk-swizzled
    __shared__ unsigned short codes[2][256];

    const int tid  = threadIdx.x;
    const int part = tid >> 6;
    const int lane = tid & 63;
    const int pu   = __builtin_amdgcn_readfirstlane(part);  // SGPR wave id

    const int* __restrict__ sip = si + pu * 16;   // wave-uniform -> s_load

    // ---- per-group decomposition ----
    const int g0 = blockIdx.x * 2;
    int bb[2], ss[2], yy0[2], xx0[2];
    #pragma unroll
    for (int g = 0; g < 2; ++g) {
        const int p = (g0 + g) * 64 + lane;       // < 50176 exactly
        bb[g]  = p / SP;
        ss[g]  = p - bb[g] * SP;
        yy0[g] = ss[g] / W56;
        xx0[g] = ss[g] - yy0[g] * W56;
    }

    // ---- gathers for group 0 FIRST (cold HBM, longest latency) ----
    float v0[4][4], v1[4][4];
    {
        const float* __restrict__ xb = x + bb[0] * (CHN * SP);
        #pragma unroll
        for (int c = 0; c < 4; ++c) {
            #pragma unroll
            for (int t = 0; t < 4; ++t) {
                const int cb = pu * 4 + c;
                const int g  = sip[c * 4 + t] + cb * 36;
                const int ch = g / 9;
                const int k9 = g - ch * 9;
                const int ki = k9 / 3;
                const int dy = ki - 1;
                const int dx = (k9 - ki * 3) - 1;
                const int yv = yy0[0] + dy, xv = xx0[0] + dx;
                const bool ok = ((unsigned)yv < (unsigned)W56) & ((unsigned)xv < (unsigned)W56);
                const int yc = min(max(yv, 0), W56 - 1);
                const int xc = min(max(xv, 0), W56 - 1);
                const float lv = xb[ch * SP + yc * W56 + xc];
                v0[c][t] = ok ? lv : 0.0f;
            }
        }
    }

    // ---- async LUT staging: wave pu copies its 8KB quarter, 8 x 1KB ----
    {
        const char* gsrc = reinterpret_cast<const char*>(wlut) + pu * 8192 + lane * 16;
        char*       ldst = reinterpret_cast<char*>(lutLds) + pu * 8192;
        #pragma unroll
        for (int i = 0; i < 8; ++i)
            async_copy16(gsrc + i * 1024, ldst + i * 1024);
    }

    // ---- gathers for group 1 (in flight across encode g0 + barrier) ----
    {
        const float* __restrict__ xb = x + bb[1] * (CHN * SP);
        #pragma unroll
        for (int c = 0; c < 4; ++c) {
            #pragma unroll
            for (int t = 0; t < 4; ++t) {
                const int cb = pu * 4 + c;
                const int g  = sip[c * 4 + t] + cb * 36;
                const int ch = g / 9;
                const int k9 = g - ch * 9;
                const int ki = k9 / 3;
                const int dy = ki - 1;
                const int dx = (k9 - ki * 3) - 1;
                const int yv = yy0[1] + dy, xv = xx0[1] + dx;
                const bool ok = ((unsigned)yv < (unsigned)W56) & ((unsigned)xv < (unsigned)W56);
                const int yc = min(max(yv, 0), W56 - 1);
                const int xc = min(max(xv, 0), W56 - 1);
                const float lv = xb[ch * SP + yc * W56 + xc];
                v1[c][t] = ok ? lv : 0.0f;
            }
        }
    }

    // ---- breadth-first thresholds: wave-uniform -> s_load into SGPRs ----
    const float* __restrict__ svp = sv + pu * 128;
    float T0[4], T1[4][2], T2[4][4], T3[4][8];
    #pragma unroll
    for (int c = 0; c < 4; ++c) {
        const int base = c * 32;
        T0[c] = svp[base];
        #pragma unroll
        for (int j = 0; j < 2; ++j) T1[c][j] = svp[base + 8  + j];
        #pragma unroll
        for (int j = 0; j < 4; ++j) T2[c][j] = svp[base + 16 + j];
        #pragma unroll
        for (int j = 0; j < 8; ++j) T3[c][j] = svp[base + 24 + j];
    }

    // ---- encode helper (pure-VALU select tree) ----
    auto encode = [&](const float v[4][4]) -> unsigned {
        unsigned code = 0;
        #pragma unroll
        for (int c = 0; c < 4; ++c) {
            const bool b0 = v[c][0] >= T0[c];
            const float t1 = b0 ? T1[c][1] : T1[c][0];
            const bool b1 = v[c][1] >= t1;
            const float s01 = b1 ? T2[c][1] : T2[c][0];
            const float s23 = b1 ? T2[c][3] : T2[c][2];
            const bool b2 = v[c][2] >= (b0 ? s23 : s01);
            const float w0 = b2 ? T3[c][1] : T3[c][0];
            const float w1 = b2 ? T3[c][3] : T3[c][2];
            const float w2 = b2 ? T3[c][5] : T3[c][4];
            const float w3 = b2 ? T3[c][7] : T3[c][6];
            const float z0 = b1 ? w1 : w0;
            const float z1 = b1 ? w3 : w2;
            const bool b3 = v[c][3] >= (b0 ? z1 : z0);
            const int e = ((int)b0 << 3) | ((int)b1 << 2) | ((int)b2 << 1) | (int)b3;
            code |= (unsigned)e << (4 * c);
        }
        return code;
    };

    // ---- decode+store helper: wave 'part' = channel quarter q ----
    const int q = part;
    auto decode_store = [&](int slot, int gi) {
        const unsigned cd0 = codes[slot][lane];
        const unsigned cd1 = codes[slot][64 + lane];
        const unsigned cd2 = codes[slot][128 + lane];
        const unsigned cd3 = codes[slot][192 + lane];

        __half2 acc[8];
        #pragma unroll
        for (int r = 0; r < 8; ++r) acc[r] = __half2{__half(0.0f), __half(0.0f)};

        #pragma unroll
        for (int cb = 0; cb < 16; ++cb) {
            const unsigned cw = (cb < 4) ? cd0 : (cb < 8) ? cd1 : (cb < 12) ? cd2 : cd3;
            const int e   = (int)((cw >> ((cb & 3) * 4)) & 15u);
            const int row = cb * 16 + e;
            const int swz = e & 7;                     // row & 7 == e & 7
            const int c0  = (2 * q) ^ swz;             // chunk: halves [16q,16q+8)
            const int c1  = c0 ^ 1;                    // chunk: halves [16q+8,16q+16)
            const __half2* __restrict__ base = &lutLds[row * 32];
            const float4 ra = *reinterpret_cast<const float4*>(base + c0 * 4);
            const float4 rb = *reinterpret_cast<const float4*>(base + c1 * 4);
            const __half2* ha = reinterpret_cast<const __half2*>(&ra);
            const __half2* hb = reinterpret_cast<const __half2*>(&rb);
            #pragma unroll
            for (int r = 0; r < 4; ++r) {
                acc[r]     += ha[r];
                acc[4 + r] += hb[r];
            }
        }

        float* __restrict__ op = out + bb[gi] * (CHN * SP) + (q * 16) * SP + ss[gi];
        const float* __restrict__ bq = bias + q * 16;
        #pragma unroll
        for (int r = 0; r < 8; ++r) {
            const float2 f = __half22float2(acc[r]);
            op[(2 * r)     * SP] = f.x + bq[2 * r];
            op[(2 * r + 1) * SP] = f.y + bq[2 * r + 1];
        }
    };

    // ---- schedule ----
    codes[0][part * 64 + lane] = (unsigned short)encode(v0);
    __syncthreads();                       // LUT staged + codes[0] ready

    codes[1][part * 64 + lane] = (unsigned short)encode(v1);  // VALU, hides g1 load wait
    decode_store(0, 0);

    __syncthreads();                       // codes[1] ready
    decode_store(1, 1);
}

extern "C" void kernel_launch(void* const* d_in, const int* in_sizes, int n_in,
                              void* d_out, int out_size, void* d_ws, size_t ws_size,
                              hipStream_t stream) {
    const float* x  = (const float*)d_in[0];
    const int*   si = (const int*)  d_in[1];
    const float* sv = (const float*)d_in[2];
    const float* lt = (const float*)d_in[3];
    const float* bs = (const float*)d_in[4];
    float* o = (float*)d_out;
    __half* wlut = (__half*)d_ws;   // 32KB of workspace

    lut_prep<<<dim3(8), dim3(256), 0, stream>>>(lt, wlut);
    maddness_fused<<<dim3(392), dim3(256), 0, stream>>>(x, si, sv, wlut, bs, o);
}